// Round 3
// baseline (360.885 us; speedup 1.0000x reference)
//
#include <hip/hip_runtime.h>
#include <hip/hip_bf16.h>

#define HID 128

typedef unsigned int uint;
typedef unsigned short ushort;
typedef short short8 __attribute__((ext_vector_type(8)));
typedef float f32x4 __attribute__((ext_vector_type(4)));

static inline int cdiv_i(long a, long b) { return (int)((a + b - 1) / b); }
static inline int imax_i(int a, int b) { return a > b ? a : b; }

__device__ __forceinline__ float bf2f(uint hi) {
    return __builtin_bit_cast(float, hi << 16);
}
__device__ __forceinline__ ushort f2bf(float f) {  // RNE
    uint u = __builtin_bit_cast(uint, f);
    u = (u + 0x7fffu + ((u >> 16) & 1u)) >> 16;
    return (ushort)u;
}

// ---------------------------------------------------------------------------
// CSR descriptor (8 lists; self-loops implicit in reserved last slot).
// ---------------------------------------------------------------------------
struct CsrDesc {
    const int* esrc[8];
    const int* edst[8];
    int ebase[9];
    int nbase[9];
    int totE;
};

// ---------------------------------------------------------------------------
// MFMA GEMM machinery. No LDS: Wt (bf16, [n][k], 32 KB) is read directly
// through L1/L2 — it is shared by every block, so it stays cache-resident.
// ---------------------------------------------------------------------------
template <typename AT>
__device__ __forceinline__ void load_afrag(const AT* __restrict__ A, long row,
                                           int koff, short8& af) {
    if constexpr (__is_same(AT, ushort)) {
        const uint4 raw = *(const uint4*)(A + row * 128 + koff);
        af = __builtin_bit_cast(short8, raw);
    } else {
        const float4* p = (const float4*)(A + row * 128 + koff);
        const float4 x0 = p[0], x1 = p[1];
        af[0] = (short)f2bf(x0.x); af[1] = (short)f2bf(x0.y);
        af[2] = (short)f2bf(x0.z); af[3] = (short)f2bf(x0.w);
        af[4] = (short)f2bf(x1.x); af[5] = (short)f2bf(x1.y);
        af[6] = (short)f2bf(x1.z); af[7] = (short)f2bf(x1.w);
    }
}

// ---------------------------------------------------------------------------
// Ontology GEMM with fused attention-score epilogue (device body)
// ---------------------------------------------------------------------------
struct GOnto {
    const ushort* Wt0; const ushort* Wt1; const ushort* Wt2;
    const float* s0; const float* s1; const float* s2;
    const float* d0; const float* d1; const float* d2;
    int bs1, bs2;
    int r1, r2, r3;
};

template <typename AT>
__device__ void gemm_onto_dev(int b, const AT* __restrict__ x0,
                              const AT* __restrict__ x1, const AT* __restrict__ x2,
                              const GOnto& g, ushort* __restrict__ H,
                              float* __restrict__ as_o, float* __restrict__ ad_o) {
    const int gid = (b >= g.bs1) + (b >= g.bs2);
    const ushort* Wt = (gid == 0) ? g.Wt0 : (gid == 1) ? g.Wt1 : g.Wt2;
    const float* avs = (gid == 0) ? g.s0 : (gid == 1) ? g.s1 : g.s2;
    const float* avd = (gid == 0) ? g.d0 : (gid == 1) ? g.d1 : g.d2;
    const AT* Ag = (gid == 0) ? x0 : (gid == 1) ? x1 : x2;
    const int bloc = b - ((gid == 0) ? 0 : (gid == 1) ? g.bs1 : g.bs2);
    const long rb = (gid == 0) ? 0 : (gid == 1) ? g.r1 : g.r2;
    const long Mg = ((gid == 0) ? g.r1 : (gid == 1) ? g.r2 : g.r3) - rb;

    const int tid = threadIdx.x;
    const int wave = tid >> 6, lane = tid & 63;
    const int r = lane & 15, q = lane >> 4;
    const long m0 = (long)bloc * 128 + wave * 32;

    f32x4 acc[2][8];
#pragma unroll
    for (int mi = 0; mi < 2; ++mi)
#pragma unroll
        for (int ni = 0; ni < 8; ++ni) acc[mi][ni] = (f32x4)0.f;

#pragma unroll
    for (int t = 0; t < 4; ++t) {
        const int koff = t * 32 + q * 8;
        short8 bfr[8];
#pragma unroll
        for (int ni = 0; ni < 8; ++ni) {
            const uint4 raw = *(const uint4*)(Wt + (ni * 16 + r) * 128 + koff);
            bfr[ni] = __builtin_bit_cast(short8, raw);
        }
#pragma unroll
        for (int mi = 0; mi < 2; ++mi) {
            long row = m0 + mi * 16 + r;
            if (row >= Mg) row = Mg - 1;
            short8 af;
            load_afrag<AT>(Ag, row, koff, af);
#pragma unroll
            for (int ni = 0; ni < 8; ++ni)
                acc[mi][ni] = __builtin_amdgcn_mfma_f32_16x16x32_bf16(
                    af, bfr[ni], acc[mi][ni], 0, 0, 0);
        }
    }

    ushort* Hg = H + rb * 128;
#pragma unroll
    for (int mi = 0; mi < 2; ++mi) {
#pragma unroll
        for (int ni = 0; ni < 8; ++ni) {
            const int col = ni * 16 + r;
#pragma unroll
            for (int reg = 0; reg < 4; ++reg) {
                const long row = m0 + mi * 16 + q * 4 + reg;
                if (row < Mg) Hg[row * 128 + col] = f2bf(acc[mi][ni][reg]);
            }
        }
    }

    float asv[8], adv[8];
#pragma unroll
    for (int ni = 0; ni < 8; ++ni) {
        asv[ni] = avs[ni * 16 + r];
        adv[ni] = avd[ni * 16 + r];
    }
#pragma unroll
    for (int mi = 0; mi < 2; ++mi) {
#pragma unroll
        for (int reg = 0; reg < 4; ++reg) {
            float ps = 0.f, pd = 0.f;
#pragma unroll
            for (int ni = 0; ni < 8; ++ni) {
                ps += acc[mi][ni][reg] * asv[ni];
                pd += acc[mi][ni][reg] * adv[ni];
            }
#pragma unroll
            for (int o = 1; o < 16; o <<= 1) {
                ps += __shfl_xor(ps, o);
                pd += __shfl_xor(pd, o);
            }
            const long row = m0 + mi * 16 + q * 4 + reg;
            if (r == 0 && row < Mg) {
                as_o[rb + row] = ps;
                ad_o[rb + row] = pd;
            }
        }
    }
}

__global__ __launch_bounds__(256) void gemm_onto_l2(const ushort* __restrict__ x0,
                                                    const ushort* __restrict__ x1,
                                                    const ushort* __restrict__ x2,
                                                    GOnto g, ushort* __restrict__ H,
                                                    float* __restrict__ as_o,
                                                    float* __restrict__ ad_o) {
    gemm_onto_dev<ushort>(blockIdx.x, x0, x1, x2, g, H, as_o, ad_o);
}

// ---------------------------------------------------------------------------
// Patient GEMM with fused allemb gather.
// ---------------------------------------------------------------------------
struct EmbSrc {
    const float* spec; const ushort* oE;
    const int* m0; const int* m1; const int* m2;
    int lb2, lb3, r1, r2;
};

__device__ __forceinline__ short8 load_emb(const EmbSrc& e, long row, int koff) {
    short8 af;
    if (row == 0) {
        const float4* pp = (const float4*)(e.spec + koff);
        const float4 x0 = pp[0], x1 = pp[1];
        af[0] = (short)f2bf(x0.x); af[1] = (short)f2bf(x0.y);
        af[2] = (short)f2bf(x0.z); af[3] = (short)f2bf(x0.w);
        af[4] = (short)f2bf(x1.x); af[5] = (short)f2bf(x1.y);
        af[6] = (short)f2bf(x1.z); af[7] = (short)f2bf(x1.w);
        return af;
    }
    const int r = (int)row;
    const int seg = (r >= e.lb2) + (r >= e.lb3);
    const int local = r - ((seg == 0) ? 1 : (seg == 1) ? e.lb2 : e.lb3);
    const int* mp = (seg == 0) ? e.m0 : (seg == 1) ? e.m1 : e.m2;
    const int rb = (seg == 0) ? 0 : (seg == 1) ? e.r1 : e.r2;
    const long sr = (long)rb + mp[local];
    return __builtin_bit_cast(short8, *(const uint4*)(e.oE + sr * 128 + koff));
}

__device__ void gemm_pat_tile(const EmbSrc& es, const ushort* __restrict__ Wt,
                              ushort* __restrict__ C, long m0blk, long rowEnd) {
    const int tid = threadIdx.x;
    const int wave = tid >> 6, lane = tid & 63;
    const int r = lane & 15, q = lane >> 4;
    const long m0 = m0blk + wave * 32;

    f32x4 acc[2][8];
#pragma unroll
    for (int mi = 0; mi < 2; ++mi)
#pragma unroll
        for (int ni = 0; ni < 8; ++ni) acc[mi][ni] = (f32x4)0.f;

#pragma unroll
    for (int t = 0; t < 4; ++t) {
        const int koff = t * 32 + q * 8;
        short8 bfr[8];
#pragma unroll
        for (int ni = 0; ni < 8; ++ni) {
            const uint4 raw = *(const uint4*)(Wt + (ni * 16 + r) * 128 + koff);
            bfr[ni] = __builtin_bit_cast(short8, raw);
        }
#pragma unroll
        for (int mi = 0; mi < 2; ++mi) {
            long row = m0 + mi * 16 + r;
            if (row >= rowEnd) row = rowEnd - 1;
            const short8 af = load_emb(es, row, koff);
#pragma unroll
            for (int ni = 0; ni < 8; ++ni)
                acc[mi][ni] = __builtin_amdgcn_mfma_f32_16x16x32_bf16(
                    af, bfr[ni], acc[mi][ni], 0, 0, 0);
        }
    }

#pragma unroll
    for (int mi = 0; mi < 2; ++mi) {
#pragma unroll
        for (int ni = 0; ni < 8; ++ni) {
            const int col = ni * 16 + r;
#pragma unroll
            for (int reg = 0; reg < 4; ++reg) {
                const long row = m0 + mi * 16 + q * 4 + reg;
                if (row < rowEnd) C[row * 128 + col] = f2bf(acc[mi][ni][reg]);
            }
        }
    }
}

__global__ __launch_bounds__(256) void gemm_pat(EmbSrc es,
                                                const ushort* __restrict__ Wt,
                                                ushort* __restrict__ C, int M) {
    const long m0 = (long)blockIdx.x * 256;
    gemm_pat_tile(es, Wt, C, m0, M);
    if (m0 + 128 < M) gemm_pat_tile(es, Wt, C, m0 + 128, M);
}

// ---------------------------------------------------------------------------
// Device bodies for packed small kernels
// ---------------------------------------------------------------------------
__device__ __forceinline__ void fold1_dev(int idx, const float* __restrict__ W2,
                                          const float* __restrict__ b2,
                                          const float* __restrict__ W3,
                                          float* __restrict__ W23b) {
    if (idx >= 129 * 128) return;
    const int i = idx >> 7, j = idx & 127;
    const float* a = (i < 128) ? (W2 + i * 128) : b2;
    float s = 0.f;
#pragma unroll 8
    for (int k = 0; k < 128; ++k) s += a[k] * W3[k * 128 + j];
    W23b[idx] = s;
}

// fold2: rows 0..127 -> WpT (bf16, transposed [n][k]); row 128 -> c1;
// row 129 -> c2 (= W23b row 128).
__device__ __forceinline__ void fold2_dev(int idx, const float* __restrict__ W1,
                                          const float* __restrict__ b1,
                                          const float* __restrict__ W23b,
                                          ushort* __restrict__ WpT,
                                          float* __restrict__ cbuf) {
    if (idx >= 130 * 128) return;
    const int i = idx >> 7, j = idx & 127;
    if (i == 129) { cbuf[128 + j] = W23b[128 * 128 + j]; return; }
    const float* a = (i < 128) ? (W1 + i * 128) : b1;
    float s = 0.f;
#pragma unroll 8
    for (int k = 0; k < 128; ++k) s += a[k] * W23b[k * 128 + j];
    if (i < 128) WpT[j * 128 + i] = f2bf(s);
    else cbuf[j] = s;
}

__device__ __forceinline__ void mark_dev(int i, const int* __restrict__ lEg,
                                         const int* __restrict__ rEg, int EP,
                                         int NP, int* __restrict__ mk,
                                         int testBit, int setBit) {
    int src, dst;
    if (i < 2 * EP) {
        const int side = i >= EP;
        const int e = i - side * EP;
        const int* eg = side ? rEg : lEg;
        src = side * NP + eg[e];
        dst = side * NP + eg[EP + e];
    } else if (i < 2 * EP + 2 * NP) {
        src = dst = i - 2 * EP;
    } else return;
    if (mk[dst] & testBit) atomicOr(&mk[src], setBit);
}

__device__ __forceinline__ void csr_count_dev(int i, const CsrDesc& d,
                                              int* __restrict__ cnt,
                                              int* __restrict__ pos) {
    if (i >= d.totE) return;
    int li = 0;
#pragma unroll
    for (int k = 1; k < 8; ++k) li += (i >= d.ebase[k]);
    const int v = d.nbase[li] + d.edst[li][i - d.ebase[li]];
    pos[i] = atomicAdd(&cnt[v], 1);
}

// ---------------------------------------------------------------------------
// L1: fold1 || wtrans (3 ont W) || init (cnt=0, first_node+mk+gf)
// ---------------------------------------------------------------------------
struct PackPrep {
    const float* W2; const float* b2; const float* W3; float* W23b;
    const float* wsrc[3]; ushort* wt_out;
    int* cnt; int NV;
    const int* bL; const int* bR; int NP;
    int* gfL; int* gfR; int* mk;
    int nbF1, nbWT, nbInit;
};

__global__ __launch_bounds__(256) void k_prep(PackPrep p) {
    const int b = blockIdx.x, tid = threadIdx.x;
    if (b < p.nbF1) {
        fold1_dev(b * 256 + tid, p.W2, p.b2, p.W3, p.W23b);
    } else if (b < p.nbF1 + p.nbWT) {
        const int idx = (b - p.nbF1) * 256 + tid;
        if (idx < 3 * 16384) {
            const int m = idx >> 14;
            const int e = idx & 16383;
            const int n = e >> 7, k = e & 127;
            p.wt_out[idx] = f2bf(p.wsrc[m][k * 128 + n]);
        }
    } else {
        const int i = (b - p.nbF1 - p.nbWT) * 256 + tid;
        if (i < p.NV) p.cnt[i] = 0;
        if (i < 2 * p.NP) {
            const int side = i >= p.NP;
            const int ii = i - (side ? p.NP : 0);
            const int* bb = side ? p.bR : p.bL;
            int* gf = side ? p.gfR : p.gfL;
            const int cur = bb[ii];
            const int prev = (ii == 0) ? -1 : bb[ii - 1];
            int m = 0;
            if (cur > prev) {
                for (int g = prev + 1; g <= cur; ++g) gf[g] = ii;
                m = 1;
            }
            p.mk[i] = m;
        }
    }
}

// ---------------------------------------------------------------------------
// L2: big pack, zero LDS: ontology GEMM L1 (first, early start) || fold2 ||
// csr_count || mark1. Scatter latency hides under the GEMM; no LDS means the
// scatter blocks are only VGPR-limited.
// ---------------------------------------------------------------------------
struct PackBig {
    const float* x0; const float* x1; const float* x2;
    GOnto go; ushort* H; float* as_o; float* ad_o;
    const float* W1; const float* b1; const float* W23b;
    ushort* WpT; float* cbuf;
    CsrDesc dsc; int* cnt; int* pos;
    const int* lEg; const int* rEg; int EP; int NP; int* mk;
    int nbGemm, nbF2, nbCnt;
};

__global__ __launch_bounds__(256) void k_big1(PackBig p) {
    const int b = blockIdx.x, tid = threadIdx.x;
    if (b < p.nbGemm) {
        gemm_onto_dev<float>(b, p.x0, p.x1, p.x2, p.go, p.H, p.as_o, p.ad_o);
    } else if (b < p.nbGemm + p.nbF2) {
        fold2_dev((b - p.nbGemm) * 256 + tid, p.W1, p.b1, p.W23b, p.WpT, p.cbuf);
    } else if (b < p.nbGemm + p.nbF2 + p.nbCnt) {
        csr_count_dev((b - p.nbGemm - p.nbF2) * 256 + tid, p.dsc, p.cnt, p.pos);
    } else {
        mark_dev((b - p.nbGemm - p.nbF2 - p.nbCnt) * 256 + tid, p.lEg, p.rEg,
                 p.EP, p.NP, p.mk, 1, 2);
    }
}

// ---------------------------------------------------------------------------
// L3: scan_tile (1024 elems/block, emits dinv) || mark2
// ---------------------------------------------------------------------------
__device__ void scan_tile_dev(const int* __restrict__ in, int* __restrict__ out,
                              int* __restrict__ bsum, int n, int pn0, int pcnt,
                              float* __restrict__ dinv, int tb, int tid,
                              int* sbuf) {
    const int base = tb * 1024 + tid * 4;
    int v[4];
    int s = 0;
#pragma unroll
    for (int k = 0; k < 4; ++k) {
        const int i = base + k;
        v[k] = (i < n) ? (in[i] + 1) : 0;
        if (i >= pn0 && i < pn0 + pcnt)
            dinv[i - pn0] = rsqrtf(fmaxf((float)v[k], 1e-12f));
        s += v[k];
    }
    sbuf[tid] = s;
    __syncthreads();
    int x = s;
    for (int o = 1; o < 256; o <<= 1) {
        const int t = (tid >= o) ? sbuf[tid - o] : 0;
        __syncthreads();
        x += t;
        sbuf[tid] = x;
        __syncthreads();
    }
    int run = x - s;  // exclusive prefix across threads
#pragma unroll
    for (int k = 0; k < 4; ++k) {
        const int i = base + k;
        if (i < n) out[i] = run;
        run += v[k];
    }
    if (tid == 255) bsum[tb] = x;
}

struct PackScan {
    const int* cnt; int* offs; int* bsum;
    int NV; int pn0; int pcnt; float* dinv;
    const int* lEg; const int* rEg; int EP; int NP; int* mk;
    int nbScan;
};

__global__ __launch_bounds__(256) void k_scan(PackScan p) {
    __shared__ int sbuf[256];
    const int b = blockIdx.x, tid = threadIdx.x;
    if (b < p.nbScan) {
        scan_tile_dev(p.cnt, p.offs, p.bsum, p.NV, p.pn0, p.pcnt, p.dinv, b,
                      tid, sbuf);
    } else {
        mark_dev((b - p.nbScan) * 256 + tid, p.lEg, p.rEg, p.EP, p.NP, p.mk,
                 2, 4);
    }
}

// ---------------------------------------------------------------------------
// L4: fused bsum-prefix + add.
// ---------------------------------------------------------------------------
__global__ __launch_bounds__(256) void k_scanfin(int* __restrict__ out,
                                                 const int* __restrict__ bsum,
                                                 int n, int nbData) {
    __shared__ int sbuf[256];
    const int tb = blockIdx.x, tid = threadIdx.x;
    int pLim = tb < nbData ? tb : nbData;
    int pth = 0;
    for (int j = tid; j < pLim; j += 256) pth += bsum[j];
    sbuf[tid] = pth;
    __syncthreads();
    for (int o = 128; o > 0; o >>= 1) {
        if (tid < o) sbuf[tid] += sbuf[tid + o];
        __syncthreads();
    }
    const int prefix = sbuf[0];
    const int base = tb * 1024 + tid * 4;
#pragma unroll
    for (int k = 0; k < 4; ++k) {
        const int i = base + k;
        if (i < n) out[i] += prefix;
        else if (i == n) out[i] = prefix + ((tb < nbData) ? bsum[tb] : 0);
    }
}

// ---------------------------------------------------------------------------
// Range-parameterized CSR fill.
// ---------------------------------------------------------------------------
struct FillP {
    CsrDesc dsc;
    const int* offs; const int* pos; const int* cnt;
    int* srcl; int4* pedge; const float* dinv;
    const int* lx; const int* rx; const int* mk;
    int NP, pB;
    int eStart, eCount, vStart, vCount;
};

__device__ void fill_dev(const FillP& f, int idx) {
    int v, s, li, cidx;
    if (idx < f.eCount) {
        const int i = f.eStart + idx;
        li = 0;
#pragma unroll
        for (int k = 1; k < 8; ++k) li += (i >= f.dsc.ebase[k]);
        const int j = i - f.dsc.ebase[li];
        v = f.dsc.nbase[li] + f.dsc.edst[li][j];
        s = f.dsc.esrc[li][j];
        cidx = f.offs[v] + f.pos[i];
    } else if (idx < f.eCount + f.vCount) {
        v = f.vStart + (idx - f.eCount);
        li = 0;
#pragma unroll
        for (int k = 1; k < 8; ++k) li += (v >= f.dsc.nbase[k]);
        s = v - f.dsc.nbase[li];
        cidx = f.offs[v] + f.cnt[v];
    } else return;
    if (li >= 6) {
        const int n2l = v - f.dsc.nbase[6];
        if (f.mk[n2l] == 0) return;   // edge list never read
        const int sg = (li - 6) * f.NP + s;
        int4 rec;
        rec.x = sg;
        rec.y = (li == 7 ? f.rx : f.lx)[s];
        rec.z = __float_as_int(f.dinv[n2l] * f.dinv[sg]);
        rec.w = 0;
        f.pedge[cidx - f.pB] = rec;
    } else {
        f.srcl[cidx] = s;
    }
}

__global__ __launch_bounds__(256) void k_fill(FillP f) {
    fill_dev(f, blockIdx.x * 256 + threadIdx.x);
}

// ---------------------------------------------------------------------------
// GAT aggregation: quarter-wave per node (device body).
// ---------------------------------------------------------------------------
struct GatP {
    int r1, r2;
    int ob0, ob1, ob2;
    const float* b0; const float* b1; const float* b2;
};

__device__ __forceinline__ void acc8(float* acc, float w, const uint4 v) {
    acc[0] += w * bf2f(v.x & 0xffff);
    acc[1] += w * bf2f(v.x >> 16);
    acc[2] += w * bf2f(v.y & 0xffff);
    acc[3] += w * bf2f(v.y >> 16);
    acc[4] += w * bf2f(v.z & 0xffff);
    acc[5] += w * bf2f(v.z >> 16);
    acc[6] += w * bf2f(v.w & 0xffff);
    acc[7] += w * bf2f(v.w >> 16);
}

__device__ void gat_dev(int node, int ql, const ushort* __restrict__ h,
                        const float* __restrict__ as, const float* __restrict__ ad,
                        const int* __restrict__ offs, const int* __restrict__ srcl,
                        const GatP& p, ushort* __restrict__ out, int Mtot) {
    if (node >= Mtot) return;
    const int gid = (node >= p.r1) + (node >= p.r2);
    const int rb = (gid == 0) ? 0 : (gid == 1) ? p.r1 : p.r2;
    const int ob = (gid == 0) ? p.ob0 : (gid == 1) ? p.ob1 : p.ob2;
    const float* bias = (gid == 0) ? p.b0 : (gid == 1) ? p.b1 : p.b2;
    const int local = node - rb;
    const int beg = offs[ob + local], end = offs[ob + local + 1];
    const float adv = ad[node];
    float m = -1e30f;
    for (int j = beg; j < end; ++j) {
        float e = as[rb + srcl[j]] + adv;
        e = (e > 0.f) ? e : 0.2f * e;
        m = fmaxf(m, e);
    }
    float denom = 0.f;
    float acc[8] = {0.f, 0.f, 0.f, 0.f, 0.f, 0.f, 0.f, 0.f};
    int j = beg;
    for (; j + 2 <= end; j += 2) {
        const int s0 = srcl[j], s1 = srcl[j + 1];
        float e0 = as[rb + s0] + adv; e0 = (e0 > 0.f) ? e0 : 0.2f * e0;
        float e1 = as[rb + s1] + adv; e1 = (e1 > 0.f) ? e1 : 0.2f * e1;
        const float w0 = __expf(e0 - m), w1 = __expf(e1 - m);
        const uint4 v0 = *(const uint4*)(h + (size_t)(rb + s0) * 128 + ql * 8);
        const uint4 v1 = *(const uint4*)(h + (size_t)(rb + s1) * 128 + ql * 8);
        denom += w0 + w1;
        acc8(acc, w0, v0);
        acc8(acc, w1, v1);
    }
    if (j < end) {
        const int s0 = srcl[j];
        float e0 = as[rb + s0] + adv; e0 = (e0 > 0.f) ? e0 : 0.2f * e0;
        const float w0 = __expf(e0 - m);
        const uint4 v0 = *(const uint4*)(h + (size_t)(rb + s0) * 128 + ql * 8);
        denom += w0;
        acc8(acc, w0, v0);
    }
    const float inv = 1.f / denom;
    const float4 bv0 = *(const float4*)(bias + ql * 8);
    const float4 bv1 = *(const float4*)(bias + ql * 8 + 4);
    uint4 o;
    o.x = (uint)f2bf(acc[0] * inv + bv0.x) | ((uint)f2bf(acc[1] * inv + bv0.y) << 16);
    o.y = (uint)f2bf(acc[2] * inv + bv0.z) | ((uint)f2bf(acc[3] * inv + bv0.w) << 16);
    o.z = (uint)f2bf(acc[4] * inv + bv1.x) | ((uint)f2bf(acc[5] * inv + bv1.y) << 16);
    o.w = (uint)f2bf(acc[6] * inv + bv1.z) | ((uint)f2bf(acc[7] * inv + bv1.w) << 16);
    *(uint4*)(out + (size_t)node * 128 + ql * 8) = o;
}

__global__ __launch_bounds__(256) void gat_all(const ushort* __restrict__ h,
                                               const float* __restrict__ as,
                                               const float* __restrict__ ad,
                                               const int* __restrict__ offs,
                                               const int* __restrict__ srcl,
                                               GatP p, ushort* __restrict__ out,
                                               int Mtot) {
    gat_dev(blockIdx.x * 16 + (threadIdx.x >> 4), threadIdx.x & 15, h, as, ad,
            offs, srcl, p, out, Mtot);
}

// L6: gat layer 1 || patient CSR fill
struct GatFill {
    const ushort* h; const float* as; const float* ad;
    const int* offs; const int* srcl;
    GatP gp; ushort* out; int Mtot; int nbGat;
    FillP f;
};

__global__ __launch_bounds__(256) void k_gat_fill(GatFill g) {
    const int b = blockIdx.x, tid = threadIdx.x;
    if (b < g.nbGat) {
        gat_dev(b * 16 + (tid >> 4), tid & 15, g.h, g.as, g.ad, g.offs, g.srcl,
                g.gp, g.out, g.Mtot);
    } else {
        fill_dev(g.f, (b - g.nbGat) * 256 + tid);
    }
}

// ---------------------------------------------------------------------------
// GCN aggregations: quarter-wave per node, early exit on mk bit.
// ---------------------------------------------------------------------------
__global__ __launch_bounds__(256) void gcn_agg1(const ushort* __restrict__ A3,
                                                const int4* __restrict__ pedge,
                                                const int* __restrict__ offs6,
                                                const float* __restrict__ c1,
                                                ushort* __restrict__ t1,
                                                const int* __restrict__ mk,
                                                int NP2, int pB) {
    const int n2 = blockIdx.x * 16 + (threadIdx.x >> 4);
    const int ql = threadIdx.x & 15;
    if (n2 >= NP2) return;
    if ((mk[n2] & 4) == 0) return;   // t1 row never read
    const int beg = offs6[n2] - pB, end = offs6[n2 + 1] - pB;
    float acc[8] = {0.f, 0.f, 0.f, 0.f, 0.f, 0.f, 0.f, 0.f};
    int j = beg;
    for (; j + 2 <= end; j += 2) {
        const int4 r0 = pedge[j], r1 = pedge[j + 1];
        const float w0 = __int_as_float(r0.z), w1 = __int_as_float(r1.z);
        const uint4 v0 = *(const uint4*)(A3 + (size_t)r0.y * 128 + ql * 8);
        const uint4 v1 = *(const uint4*)(A3 + (size_t)r1.y * 128 + ql * 8);
        acc8(acc, w0, v0);
        acc8(acc, w1, v1);
    }
    if (j < end) {
        const int4 r0 = pedge[j];
        const uint4 v0 = *(const uint4*)(A3 + (size_t)r0.y * 128 + ql * 8);
        acc8(acc, __int_as_float(r0.z), v0);
    }
    const float4 bv0 = *(const float4*)(c1 + ql * 8);
    const float4 bv1 = *(const float4*)(c1 + ql * 8 + 4);
    uint4 o;
    o.x = (uint)f2bf(acc[0] + bv0.x) | ((uint)f2bf(acc[1] + bv0.y) << 16);
    o.y = (uint)f2bf(acc[2] + bv0.z) | ((uint)f2bf(acc[3] + bv0.w) << 16);
    o.z = (uint)f2bf(acc[4] + bv1.x) | ((uint)f2bf(acc[5] + bv1.y) << 16);
    o.w = (uint)f2bf(acc[6] + bv1.z) | ((uint)f2bf(acc[7] + bv1.w) << 16);
    *(uint4*)(t1 + (size_t)n2 * 128 + ql * 8) = o;
}

__device__ __forceinline__ void gcn_q_acc(const ushort* __restrict__ x,
                                          const int4* __restrict__ pedge,
                                          int beg, int end, int ql, float* acc) {
    int j = beg;
    for (; j + 2 <= end; j += 2) {
        const int4 r0 = pedge[j], r1 = pedge[j + 1];
        const float w0 = __int_as_float(r0.z), w1 = __int_as_float(r1.z);
        const uint4 v0 = *(const uint4*)(x + (size_t)r0.x * 128 + ql * 8);
        const uint4 v1 = *(const uint4*)(x + (size_t)r1.x * 128 + ql * 8);
        acc8(acc, w0, v0);
        acc8(acc, w1, v1);
    }
    if (j < end) {
        const int4 r0 = pedge[j];
        const uint4 v0 = *(const uint4*)(x + (size_t)r0.x * 128 + ql * 8);
        acc8(acc, __int_as_float(r0.z), v0);
    }
}

__global__ __launch_bounds__(256) void gcn_agg2(const ushort* __restrict__ t1,
                                                const int4* __restrict__ pedge,
                                                const int* __restrict__ offs6,
                                                const float* __restrict__ c2,
                                                ushort* __restrict__ t2,
                                                const int* __restrict__ mk,
                                                int NP2, int pB) {
    const int n2 = blockIdx.x * 16 + (threadIdx.x >> 4);
    const int ql = threadIdx.x & 15;
    if (n2 >= NP2) return;
    if ((mk[n2] & 2) == 0) return;   // t2 row never read
    const int beg = offs6[n2] - pB, end = offs6[n2 + 1] - pB;
    float acc[8] = {0.f, 0.f, 0.f, 0.f, 0.f, 0.f, 0.f, 0.f};
    gcn_q_acc(t1, pedge, beg, end, ql, acc);
    const float4 bv0 = *(const float4*)(c2 + ql * 8);
    const float4 bv1 = *(const float4*)(c2 + ql * 8 + 4);
    uint4 o;
    o.x = (uint)f2bf(acc[0] + bv0.x) | ((uint)f2bf(acc[1] + bv0.y) << 16);
    o.y = (uint)f2bf(acc[2] + bv0.z) | ((uint)f2bf(acc[3] + bv0.w) << 16);
    o.z = (uint)f2bf(acc[4] + bv1.x) | ((uint)f2bf(acc[5] + bv1.y) << 16);
    o.w = (uint)f2bf(acc[6] + bv1.z) | ((uint)f2bf(acc[7] + bv1.w) << 16);
    *(uint4*)(t2 + (size_t)n2 * 128 + ql * 8) = o;
}

// Fused final layer + cosine: 32 lanes per graph (16 left, 16 right).
__global__ __launch_bounds__(256) void final_cos(const ushort* __restrict__ t2,
                                                 const int4* __restrict__ pedge,
                                                 const int* __restrict__ offs6,
                                                 const int* __restrict__ gfL,
                                                 const int* __restrict__ gfR,
                                                 const float* __restrict__ b3,
                                                 float* __restrict__ out,
                                                 int B, int NP, int pB) {
    const int g = blockIdx.x * 8 + (threadIdx.x >> 5);
    const int l32 = threadIdx.x & 31;
    const int side = l32 >> 4;
    const int ql = l32 & 15;
    if (g >= B) return;
    const int n2 = (side ? NP : 0) + (side ? gfR : gfL)[g];
    const int beg = offs6[n2] - pB, end = offs6[n2 + 1] - pB;
    float acc[8] = {0.f, 0.f, 0.f, 0.f, 0.f, 0.f, 0.f, 0.f};
    gcn_q_acc(t2, pedge, beg, end, ql, acc);
    const float4 bv0 = *(const float4*)(b3 + ql * 8);
    const float4 bv1 = *(const float4*)(b3 + ql * 8 + 4);
    float v[8];
    v[0] = acc[0] + bv0.x; v[1] = acc[1] + bv0.y;
    v[2] = acc[2] + bv0.z; v[3] = acc[3] + bv0.w;
    v[4] = acc[4] + bv1.x; v[5] = acc[5] + bv1.y;
    v[6] = acc[6] + bv1.z; v[7] = acc[7] + bv1.w;
    float num = 0.f, nself = 0.f, nother = 0.f;
#pragma unroll
    for (int j = 0; j < 8; ++j) {
        const float o = __shfl_xor(v[j], 16);
        num += v[j] * o;
        nself += v[j] * v[j];
        nother += o * o;
    }
#pragma unroll
    for (int o1 = 1; o1 < 16; o1 <<= 1) {
        num += __shfl_xor(num, o1);
        nself += __shfl_xor(nself, o1);
        nother += __shfl_xor(nother, o1);
    }
    if (l32 == 0)
        out[g] = num / (fmaxf(sqrtf(nself), 1e-6f) * fmaxf(sqrtf(nother), 1e-6f));
}

// ---------------------------------------------------------------------------
extern "C" void kernel_launch(void* const* d_in, const int* in_sizes, int n_in,
                              void* d_out, int out_size, void* d_ws, size_t ws_size,
                              hipStream_t stream) {
    (void)n_in; (void)ws_size;
    const float* spec = (const float*)d_in[0];
    const float* tabs[3] = {(const float*)d_in[1], (const float*)d_in[2], (const float*)d_in[3]};
    const float* ontW[3] = {(const float*)d_in[4], (const float*)d_in[8], (const float*)d_in[12]};
    const float* ontAs[3] = {(const float*)d_in[5], (const float*)d_in[9], (const float*)d_in[13]};
    const float* ontAd[3] = {(const float*)d_in[6], (const float*)d_in[10], (const float*)d_in[14]};
    const float* ontB[3] = {(const float*)d_in[7], (const float*)d_in[11], (const float*)d_in[15]};
    const float* gcnW[3] = {(const float*)d_in[16], (const float*)d_in[18], (const float*)d_in[20]};
    const float* gcnB[3] = {(const float*)d_in[17], (const float*)d_in[19], (const float*)d_in[21]};
    const int* e1s[3] = {(const int*)d_in[22], (const int*)d_in[24], (const int*)d_in[26]};
    const int* e2s[3] = {(const int*)d_in[23], (const int*)d_in[25], (const int*)d_in[27]};
    const int* maps[3] = {(const int*)d_in[28], (const int*)d_in[29], (const int*)d_in[30]};
    const int* left_x = (const int*)d_in[31];
    const int* right_x = (const int*)d_in[32];
    const int* left_eg = (const int*)d_in[33];
    const int* right_eg = (const int*)d_in[34];
    const int* left_batch = (const int*)d_in[35];
    const int* right_batch = (const int*)d_in[36];

    int Ms[3] = {in_sizes[1] / HID, in_sizes[2] / HID, in_sizes[3] / HID};
    int E1s[3] = {in_sizes[22] / 2, in_sizes[24] / 2, in_sizes[26] / 2};
    int E2s[3] = {in_sizes[23] / 2, in_sizes[25] / 2, in_sizes[27] / 2};
    int Ls[3] = {in_sizes[28], in_sizes[29], in_sizes[30]};
    const int NP = in_sizes[31];
    const int EP = in_sizes[33] / 2;
    const int B = out_size;
    const long ALL = 1 + (long)Ls[0] + Ls[1] + Ls[2];
    const int Mtot = Ms[0] + Ms[1] + Ms[2];
    const int r1 = Ms[0], r2 = Ms[0] + Ms[1];

    // ---- batched CSR descriptor ----
    CsrDesc dsc;
    int eCnt[8], nCnt[8];
    for (int i = 0; i < 3; ++i) {
        dsc.esrc[2 * i] = e1s[i];     dsc.edst[2 * i] = e1s[i] + E1s[i];
        dsc.esrc[2 * i + 1] = e2s[i]; dsc.edst[2 * i + 1] = e2s[i] + E2s[i];
        eCnt[2 * i] = E1s[i]; eCnt[2 * i + 1] = E2s[i];
        nCnt[2 * i] = Ms[i];  nCnt[2 * i + 1] = Ms[i];
    }
    dsc.esrc[6] = left_eg;  dsc.edst[6] = left_eg + EP;  eCnt[6] = EP; nCnt[6] = NP;
    dsc.esrc[7] = right_eg; dsc.edst[7] = right_eg + EP; eCnt[7] = EP; nCnt[7] = NP;
    dsc.ebase[0] = 0;
    int nb_acc = 0;
    for (int i = 0; i < 8; ++i) {
        dsc.ebase[i + 1] = dsc.ebase[i] + eCnt[i];
        dsc.nbase[i] = nb_acc;
        nb_acc += nCnt[i];
    }
    const int NV = nb_acc;
    dsc.nbase[8] = NV;
    dsc.totE = dsc.ebase[8];
    const int totEntries = dsc.totE + NV;
    const int pB = dsc.ebase[6] + dsc.nbase[6];
    const int pEntries = totEntries - pB;

    // ---- workspace layout ----
    char* ws = (char*)d_ws;
    size_t off = 0;
    auto alloc = [&](size_t bytes) -> void* {
        off = (off + 255) & ~(size_t)255;
        void* p = ws + off;
        off += bytes;
        return p;
    };
    ushort* wt4 = (ushort*)alloc((size_t)4 * 16384 * 2);   // 3 ont Wt + WpT
    float* W23b = (float*)alloc((size_t)129 * 128 * 4);
    float* cbuf = (float*)alloc((size_t)256 * 4);          // c1 | c2
    ushort* A3 = (ushort*)alloc((size_t)ALL * HID * 2);
    int* cnt = (int*)alloc((size_t)NV * 4);
    int* offs = (int*)alloc((size_t)(NV + 1) * 4);
    int* pos = (int*)alloc((size_t)dsc.totE * 4);
    int* srcl = (int*)alloc((size_t)pB * 4);
    int4* pedge = (int4*)alloc((size_t)pEntries * 16);
    int* bsum = (int*)alloc(1025 * 4);
    float* dinv = (float*)alloc((size_t)2 * NP * 4);
    float* as = (float*)alloc((size_t)Mtot * 4);
    float* ad = (float*)alloc((size_t)Mtot * 4);
    int* gfL = (int*)alloc((size_t)(B + 1) * 4);
    int* gfR = (int*)alloc((size_t)(B + 1) * 4);
    int* mk = (int*)alloc((size_t)2 * NP * 4);
    ushort* t1 = (ushort*)alloc((size_t)2 * NP * HID * 2);
    ushort* big = (ushort*)alloc((size_t)2 * NP * HID * 2);
    ushort* hbuf = big;                              // [Mtot x 128] bf16
    ushort* obuf = big + (size_t)Mtot * HID;         // [Mtot x 128] bf16
    ushort* t2 = big;                                // [2NP x 128] bf16 (later)

    const ushort* wtOnt[3] = {wt4, wt4 + 16384, wt4 + 2 * 16384};
    ushort* WpT = wt4 + 3 * 16384;
    const float* c1 = cbuf;
    const float* c2 = cbuf + 128;

    // ---- L1: prep (fold1 || wtrans x3 || init cnt/mk/gf) ----
    PackPrep pp;
    pp.W2 = gcnW[1]; pp.b2 = gcnB[1]; pp.W3 = gcnW[2]; pp.W23b = W23b;
    pp.wsrc[0] = ontW[0]; pp.wsrc[1] = ontW[1]; pp.wsrc[2] = ontW[2];
    pp.wt_out = wt4;
    pp.cnt = cnt; pp.NV = NV;
    pp.bL = left_batch; pp.bR = right_batch; pp.NP = NP;
    pp.gfL = gfL; pp.gfR = gfR; pp.mk = mk;
    pp.nbF1 = cdiv_i(129 * 128, 256);
    pp.nbWT = cdiv_i(3 * 16384, 256);
    pp.nbInit = cdiv_i(imax_i(NV, 2 * NP), 256);
    k_prep<<<pp.nbF1 + pp.nbWT + pp.nbInit, 256, 0, stream>>>(pp);

    // ---- ontology GEMM descriptor ----
    GOnto go;
    go.Wt0 = wtOnt[0]; go.Wt1 = wtOnt[1]; go.Wt2 = wtOnt[2];
    go.s0 = ontAs[0]; go.s1 = ontAs[1]; go.s2 = ontAs[2];
    go.d0 = ontAd[0]; go.d1 = ontAd[1]; go.d2 = ontAd[2];
    go.bs1 = cdiv_i(Ms[0], 128);
    go.bs2 = go.bs1 + cdiv_i(Ms[1], 128);
    const int totBlk = go.bs2 + cdiv_i(Ms[2], 128);
    go.r1 = r1; go.r2 = r2; go.r3 = Mtot;

    // ---- L2: big pack (zero LDS): gemm L1 || fold2 || csr_count || mark1 ----
    PackBig pg;
    pg.x0 = tabs[0]; pg.x1 = tabs[1]; pg.x2 = tabs[2];
    pg.go = go; pg.H = hbuf; pg.as_o = as; pg.ad_o = ad;
    pg.W1 = gcnW[0]; pg.b1 = gcnB[0]; pg.W23b = W23b;
    pg.WpT = WpT; pg.cbuf = cbuf;
    pg.dsc = dsc; pg.cnt = cnt; pg.pos = pos;
    pg.lEg = left_eg; pg.rEg = right_eg; pg.EP = EP; pg.NP = NP; pg.mk = mk;
    pg.nbGemm = totBlk;
    pg.nbF2 = cdiv_i(130 * 128, 256);
    pg.nbCnt = cdiv_i(dsc.totE, 256);
    const int nbMark = cdiv_i(2 * EP + 2 * NP, 256);
    k_big1<<<pg.nbGemm + pg.nbF2 + pg.nbCnt + nbMark, 256, 0, stream>>>(pg);

    // ---- L3: scan(+dinv) || mark2 ----
    PackScan psn;
    psn.cnt = cnt; psn.offs = offs; psn.bsum = bsum;
    psn.NV = NV; psn.pn0 = dsc.nbase[6]; psn.pcnt = 2 * NP; psn.dinv = dinv;
    psn.lEg = left_eg; psn.rEg = right_eg; psn.EP = EP; psn.NP = NP; psn.mk = mk;
    psn.nbScan = cdiv_i(NV, 1024);
    k_scan<<<psn.nbScan + nbMark, 256, 0, stream>>>(psn);

    // ---- L4: scan finalize ----
    k_scanfin<<<cdiv_i(NV + 1, 1024), 256, 0, stream>>>(offs, bsum, NV, psn.nbScan);

    // ---- shared fill params ----
    FillP fb;
    fb.dsc = dsc; fb.offs = offs; fb.pos = pos; fb.cnt = cnt;
    fb.srcl = srcl; fb.pedge = pedge; fb.dinv = dinv;
    fb.lx = left_x; fb.rx = right_x; fb.mk = mk;
    fb.NP = NP; fb.pB = pB;

    // ---- L5: ontology CSR fill (small, on critical path to gat1) ----
    FillP fo = fb;
    fo.eStart = 0;             fo.eCount = dsc.ebase[6];
    fo.vStart = 0;             fo.vCount = dsc.nbase[6];
    k_fill<<<cdiv_i(fo.eCount + fo.vCount, 256), 256, 0, stream>>>(fo);

    // ---- L6: gat layer 1 || patient CSR fill ----
    GatFill gf;
    gf.h = hbuf; gf.as = as; gf.ad = ad; gf.offs = offs; gf.srcl = srcl;
    gf.gp = GatP{r1, r2, dsc.nbase[0], dsc.nbase[2], dsc.nbase[4],
                 ontB[0], ontB[1], ontB[2]};
    gf.out = obuf; gf.Mtot = Mtot;
    gf.nbGat = cdiv_i(Mtot, 16);
    gf.f = fb;
    gf.f.eStart = dsc.ebase[6]; gf.f.eCount = dsc.totE - dsc.ebase[6];
    gf.f.vStart = dsc.nbase[6]; gf.f.vCount = NV - dsc.nbase[6];
    k_gat_fill<<<gf.nbGat + cdiv_i(gf.f.eCount + gf.f.vCount, 256), 256, 0,
                 stream>>>(gf);

    // ---- L7, L8: ontology GEMM layer 2, GAT layer 2 ----
    gemm_onto_l2<<<totBlk, 256, 0, stream>>>(obuf, obuf + (size_t)r1 * HID,
                                             obuf + (size_t)r2 * HID, go, hbuf,
                                             as, ad);
    const GatP gp1{r1, r2, dsc.nbase[1], dsc.nbase[3], dsc.nbase[5],
                   ontB[0], ontB[1], ontB[2]};
    gat_all<<<cdiv_i(Mtot, 16), 256, 0, stream>>>(hbuf, as, ad, offs, srcl, gp1,
                                                  obuf, Mtot);

    // ---- L9: patient GEMM with fused emb gather ----
    EmbSrc es;
    es.spec = spec; es.oE = obuf;
    es.m0 = maps[0]; es.m1 = maps[1]; es.m2 = maps[2];
    es.lb2 = 1 + Ls[0]; es.lb3 = 1 + Ls[0] + Ls[1];
    es.r1 = r1; es.r2 = r2;
    gemm_pat<<<cdiv_i(ALL, 256), 256, 0, stream>>>(es, WpT, A3, (int)ALL);

    // ---- L10..L12: sparsified aggregations + fused final ----
    const int* offs6 = offs + dsc.nbase[6];
    gcn_agg1<<<cdiv_i(2 * NP, 16), 256, 0, stream>>>(A3, pedge, offs6, c1, t1,
                                                     mk, 2 * NP, pB);
    gcn_agg2<<<cdiv_i(2 * NP, 16), 256, 0, stream>>>(t1, pedge, offs6, c2, t2,
                                                     mk, 2 * NP, pB);
    final_cos<<<cdiv_i(B, 8), 256, 0, stream>>>(t2, pedge, offs6, gfL, gfR,
                                                gcnB[2], (float*)d_out, B, NP, pB);
}

// Round 4
// 334.267 us; speedup vs baseline: 1.0796x; 1.0796x over previous
//
#include <hip/hip_runtime.h>
#include <hip/hip_bf16.h>

#define HID 128

typedef unsigned int uint;
typedef unsigned short ushort;
typedef short short8 __attribute__((ext_vector_type(8)));
typedef float f32x4 __attribute__((ext_vector_type(4)));

static inline int cdiv_i(long a, long b) { return (int)((a + b - 1) / b); }
static inline int imax_i(int a, int b) { return a > b ? a : b; }

__device__ __forceinline__ float bf2f(uint hi) {
    return __builtin_bit_cast(float, hi << 16);
}
__device__ __forceinline__ ushort f2bf(float f) {  // RNE
    uint u = __builtin_bit_cast(uint, f);
    u = (u + 0x7fffu + ((u >> 16) & 1u)) >> 16;
    return (ushort)u;
}

// ---------------------------------------------------------------------------
// CSR descriptor. List order: [diag_e1, proce_e1, atc_e1, diag_e2, proce_e2,
// atc_e2, left, right] so layer-1 lists are contiguous (fill split by layer).
// Self-loops implicit in reserved last slot of each node's list.
// ---------------------------------------------------------------------------
struct CsrDesc {
    const int* esrc[8];
    const int* edst[8];
    int ebase[9];
    int nbase[9];
    int totE;
};

// ---------------------------------------------------------------------------
// MFMA GEMM machinery. No LDS: Wt (bf16, [n][k], 32 KB) is read directly
// through L1/L2 — shared by every block, cache-resident.
// ---------------------------------------------------------------------------
template <typename AT>
__device__ __forceinline__ void load_afrag(const AT* __restrict__ A, long row,
                                           int koff, short8& af) {
    if constexpr (__is_same(AT, ushort)) {
        const uint4 raw = *(const uint4*)(A + row * 128 + koff);
        af = __builtin_bit_cast(short8, raw);
    } else {
        const float4* p = (const float4*)(A + row * 128 + koff);
        const float4 x0 = p[0], x1 = p[1];
        af[0] = (short)f2bf(x0.x); af[1] = (short)f2bf(x0.y);
        af[2] = (short)f2bf(x0.z); af[3] = (short)f2bf(x0.w);
        af[4] = (short)f2bf(x1.x); af[5] = (short)f2bf(x1.y);
        af[6] = (short)f2bf(x1.z); af[7] = (short)f2bf(x1.w);
    }
}

// ---------------------------------------------------------------------------
// Ontology GEMM with fused attention-score epilogue (device body)
// ---------------------------------------------------------------------------
struct GOnto {
    const ushort* Wt0; const ushort* Wt1; const ushort* Wt2;
    const float* s0; const float* s1; const float* s2;
    const float* d0; const float* d1; const float* d2;
    int bs1, bs2;
    int r1, r2, r3;
};

template <typename AT>
__device__ void gemm_onto_dev(int b, const AT* __restrict__ x0,
                              const AT* __restrict__ x1, const AT* __restrict__ x2,
                              const GOnto& g, ushort* __restrict__ H,
                              float* __restrict__ as_o, float* __restrict__ ad_o) {
    const int gid = (b >= g.bs1) + (b >= g.bs2);
    const ushort* Wt = (gid == 0) ? g.Wt0 : (gid == 1) ? g.Wt1 : g.Wt2;
    const float* avs = (gid == 0) ? g.s0 : (gid == 1) ? g.s1 : g.s2;
    const float* avd = (gid == 0) ? g.d0 : (gid == 1) ? g.d1 : g.d2;
    const AT* Ag = (gid == 0) ? x0 : (gid == 1) ? x1 : x2;
    const int bloc = b - ((gid == 0) ? 0 : (gid == 1) ? g.bs1 : g.bs2);
    const long rb = (gid == 0) ? 0 : (gid == 1) ? g.r1 : g.r2;
    const long Mg = ((gid == 0) ? g.r1 : (gid == 1) ? g.r2 : g.r3) - rb;

    const int tid = threadIdx.x;
    const int wave = tid >> 6, lane = tid & 63;
    const int r = lane & 15, q = lane >> 4;
    const long m0 = (long)bloc * 128 + wave * 32;

    f32x4 acc[2][8];
#pragma unroll
    for (int mi = 0; mi < 2; ++mi)
#pragma unroll
        for (int ni = 0; ni < 8; ++ni) acc[mi][ni] = (f32x4)0.f;

#pragma unroll
    for (int t = 0; t < 4; ++t) {
        const int koff = t * 32 + q * 8;
        short8 bfr[8];
#pragma unroll
        for (int ni = 0; ni < 8; ++ni) {
            const uint4 raw = *(const uint4*)(Wt + (ni * 16 + r) * 128 + koff);
            bfr[ni] = __builtin_bit_cast(short8, raw);
        }
#pragma unroll
        for (int mi = 0; mi < 2; ++mi) {
            long row = m0 + mi * 16 + r;
            if (row >= Mg) row = Mg - 1;
            short8 af;
            load_afrag<AT>(Ag, row, koff, af);
#pragma unroll
            for (int ni = 0; ni < 8; ++ni)
                acc[mi][ni] = __builtin_amdgcn_mfma_f32_16x16x32_bf16(
                    af, bfr[ni], acc[mi][ni], 0, 0, 0);
        }
    }

    ushort* Hg = H + rb * 128;
#pragma unroll
    for (int mi = 0; mi < 2; ++mi) {
#pragma unroll
        for (int ni = 0; ni < 8; ++ni) {
            const int col = ni * 16 + r;
#pragma unroll
            for (int reg = 0; reg < 4; ++reg) {
                const long row = m0 + mi * 16 + q * 4 + reg;
                if (row < Mg) Hg[row * 128 + col] = f2bf(acc[mi][ni][reg]);
            }
        }
    }

    float asv[8], adv[8];
#pragma unroll
    for (int ni = 0; ni < 8; ++ni) {
        asv[ni] = avs[ni * 16 + r];
        adv[ni] = avd[ni * 16 + r];
    }
#pragma unroll
    for (int mi = 0; mi < 2; ++mi) {
#pragma unroll
        for (int reg = 0; reg < 4; ++reg) {
            float ps = 0.f, pd = 0.f;
#pragma unroll
            for (int ni = 0; ni < 8; ++ni) {
                ps += acc[mi][ni][reg] * asv[ni];
                pd += acc[mi][ni][reg] * adv[ni];
            }
#pragma unroll
            for (int o = 1; o < 16; o <<= 1) {
                ps += __shfl_xor(ps, o);
                pd += __shfl_xor(pd, o);
            }
            const long row = m0 + mi * 16 + q * 4 + reg;
            if (r == 0 && row < Mg) {
                as_o[rb + row] = ps;
                ad_o[rb + row] = pd;
            }
        }
    }
}

__global__ __launch_bounds__(256) void gemm_onto_l2(const ushort* __restrict__ x0,
                                                    const ushort* __restrict__ x1,
                                                    const ushort* __restrict__ x2,
                                                    GOnto g, ushort* __restrict__ H,
                                                    float* __restrict__ as_o,
                                                    float* __restrict__ ad_o) {
    gemm_onto_dev<ushort>(blockIdx.x, x0, x1, x2, g, H, as_o, ad_o);
}

// ---------------------------------------------------------------------------
// Patient GEMM with fused allemb gather.
// ---------------------------------------------------------------------------
struct EmbSrc {
    const float* spec; const ushort* oE;
    const int* m0; const int* m1; const int* m2;
    int lb2, lb3, r1, r2;
};

__device__ __forceinline__ short8 load_emb(const EmbSrc& e, long row, int koff) {
    short8 af;
    if (row == 0) {
        const float4* pp = (const float4*)(e.spec + koff);
        const float4 x0 = pp[0], x1 = pp[1];
        af[0] = (short)f2bf(x0.x); af[1] = (short)f2bf(x0.y);
        af[2] = (short)f2bf(x0.z); af[3] = (short)f2bf(x0.w);
        af[4] = (short)f2bf(x1.x); af[5] = (short)f2bf(x1.y);
        af[6] = (short)f2bf(x1.z); af[7] = (short)f2bf(x1.w);
        return af;
    }
    const int r = (int)row;
    const int seg = (r >= e.lb2) + (r >= e.lb3);
    const int local = r - ((seg == 0) ? 1 : (seg == 1) ? e.lb2 : e.lb3);
    const int* mp = (seg == 0) ? e.m0 : (seg == 1) ? e.m1 : e.m2;
    const int rb = (seg == 0) ? 0 : (seg == 1) ? e.r1 : e.r2;
    const long sr = (long)rb + mp[local];
    return __builtin_bit_cast(short8, *(const uint4*)(e.oE + sr * 128 + koff));
}

__device__ void gemm_pat_tile(const EmbSrc& es, const ushort* __restrict__ Wt,
                              ushort* __restrict__ C, long m0blk, long rowEnd) {
    const int tid = threadIdx.x;
    const int wave = tid >> 6, lane = tid & 63;
    const int r = lane & 15, q = lane >> 4;
    const long m0 = m0blk + wave * 32;

    f32x4 acc[2][8];
#pragma unroll
    for (int mi = 0; mi < 2; ++mi)
#pragma unroll
        for (int ni = 0; ni < 8; ++ni) acc[mi][ni] = (f32x4)0.f;

#pragma unroll
    for (int t = 0; t < 4; ++t) {
        const int koff = t * 32 + q * 8;
        short8 bfr[8];
#pragma unroll
        for (int ni = 0; ni < 8; ++ni) {
            const uint4 raw = *(const uint4*)(Wt + (ni * 16 + r) * 128 + koff);
            bfr[ni] = __builtin_bit_cast(short8, raw);
        }
#pragma unroll
        for (int mi = 0; mi < 2; ++mi) {
            long row = m0 + mi * 16 + r;
            if (row >= rowEnd) row = rowEnd - 1;
            const short8 af = load_emb(es, row, koff);
#pragma unroll
            for (int ni = 0; ni < 8; ++ni)
                acc[mi][ni] = __builtin_amdgcn_mfma_f32_16x16x32_bf16(
                    af, bfr[ni], acc[mi][ni], 0, 0, 0);
        }
    }

#pragma unroll
    for (int mi = 0; mi < 2; ++mi) {
#pragma unroll
        for (int ni = 0; ni < 8; ++ni) {
            const int col = ni * 16 + r;
#pragma unroll
            for (int reg = 0; reg < 4; ++reg) {
                const long row = m0 + mi * 16 + q * 4 + reg;
                if (row < rowEnd) C[row * 128 + col] = f2bf(acc[mi][ni][reg]);
            }
        }
    }
}

__global__ __launch_bounds__(256) void gemm_pat(EmbSrc es,
                                                const ushort* __restrict__ Wt,
                                                ushort* __restrict__ C, int M) {
    const long m0 = (long)blockIdx.x * 256;
    gemm_pat_tile(es, Wt, C, m0, M);
    if (m0 + 128 < M) gemm_pat_tile(es, Wt, C, m0 + 128, M);
}

// ---------------------------------------------------------------------------
// Device bodies for packed small kernels
// ---------------------------------------------------------------------------
__device__ __forceinline__ void fold1_dev(int idx, const float* __restrict__ W2,
                                          const float* __restrict__ b2,
                                          const float* __restrict__ W3,
                                          float* __restrict__ W23b) {
    if (idx >= 129 * 128) return;
    const int i = idx >> 7, j = idx & 127;
    const float* a = (i < 128) ? (W2 + i * 128) : b2;
    float s = 0.f;
#pragma unroll 8
    for (int k = 0; k < 128; ++k) s += a[k] * W3[k * 128 + j];
    W23b[idx] = s;
}

// fold2: rows 0..127 -> WpT (bf16, transposed [n][k]); row 128 -> c1;
// row 129 -> c2 (= W23b row 128).
__device__ __forceinline__ void fold2_dev(int idx, const float* __restrict__ W1,
                                          const float* __restrict__ b1,
                                          const float* __restrict__ W23b,
                                          ushort* __restrict__ WpT,
                                          float* __restrict__ cbuf) {
    if (idx >= 130 * 128) return;
    const int i = idx >> 7, j = idx & 127;
    if (i == 129) { cbuf[128 + j] = W23b[128 * 128 + j]; return; }
    const float* a = (i < 128) ? (W1 + i * 128) : b1;
    float s = 0.f;
#pragma unroll 8
    for (int k = 0; k < 128; ++k) s += a[k] * W23b[k * 128 + j];
    if (i < 128) WpT[j * 128 + i] = f2bf(s);
    else cbuf[j] = s;
}

// Idempotent plain-store mark: all concurrent writers in a phase write the
// same value (test bit is stable within the phase), so the race is benign.
// No device-scope atomic RMW.
__device__ __forceinline__ void mark_dev(int i, const int* __restrict__ lEg,
                                         const int* __restrict__ rEg, int EP,
                                         int NP, int* __restrict__ mk,
                                         int testBit, int setBit) {
    int src, dst;
    if (i < 2 * EP) {
        const int side = i >= EP;
        const int e = i - side * EP;
        const int* eg = side ? rEg : lEg;
        src = side * NP + eg[e];
        dst = side * NP + eg[EP + e];
    } else if (i < 2 * EP + 2 * NP) {
        src = dst = i - 2 * EP;
    } else return;
    if (mk[dst] & testBit) {
        const int old = mk[src];
        if (!(old & setBit)) mk[src] = old | setBit;
    }
}

// Fire-and-forget count (no return value -> no latency chain).
__device__ __forceinline__ void csr_count_dev(int i, const CsrDesc& d,
                                              int* __restrict__ cnt) {
    if (i >= d.totE) return;
    int li = 0;
#pragma unroll
    for (int k = 1; k < 8; ++k) li += (i >= d.ebase[k]);
    const int v = d.nbase[li] + d.edst[li][i - d.ebase[li]];
    atomicAdd(&cnt[v], 1);
}

// ---------------------------------------------------------------------------
// L1: fold1 || wtrans (3 ont W) || init (cnt=0, first_node+mk+gf)
// ---------------------------------------------------------------------------
struct PackPrep {
    const float* W2; const float* b2; const float* W3; float* W23b;
    const float* wsrc[3]; ushort* wt_out;
    int* cnt; int NV;
    const int* bL; const int* bR; int NP;
    int* gfL; int* gfR; int* mk;
    int nbF1, nbWT, nbInit;
};

__global__ __launch_bounds__(256) void k_prep(PackPrep p) {
    const int b = blockIdx.x, tid = threadIdx.x;
    if (b < p.nbF1) {
        fold1_dev(b * 256 + tid, p.W2, p.b2, p.W3, p.W23b);
    } else if (b < p.nbF1 + p.nbWT) {
        const int idx = (b - p.nbF1) * 256 + tid;
        if (idx < 3 * 16384) {
            const int m = idx >> 14;
            const int e = idx & 16383;
            const int n = e >> 7, k = e & 127;
            p.wt_out[idx] = f2bf(p.wsrc[m][k * 128 + n]);
        }
    } else {
        const int i = (b - p.nbF1 - p.nbWT) * 256 + tid;
        if (i < p.NV) p.cnt[i] = 0;
        if (i < 2 * p.NP) {
            const int side = i >= p.NP;
            const int ii = i - (side ? p.NP : 0);
            const int* bb = side ? p.bR : p.bL;
            int* gf = side ? p.gfR : p.gfL;
            const int cur = bb[ii];
            const int prev = (ii == 0) ? -1 : bb[ii - 1];
            int m = 0;
            if (cur > prev) {
                for (int g = prev + 1; g <= cur; ++g) gf[g] = ii;
                m = 1;
            }
            p.mk[i] = m;
        }
    }
}

// ---------------------------------------------------------------------------
// L2: big pack, zero LDS: ontology GEMM L1 || fold2 || csr_count || mark1
// ---------------------------------------------------------------------------
struct PackBig {
    const float* x0; const float* x1; const float* x2;
    GOnto go; ushort* H; float* as_o; float* ad_o;
    const float* W1; const float* b1; const float* W23b;
    ushort* WpT; float* cbuf;
    CsrDesc dsc; int* cnt;
    const int* lEg; const int* rEg; int EP; int NP; int* mk;
    int nbGemm, nbF2, nbCnt;
};

__global__ __launch_bounds__(256) void k_big1(PackBig p) {
    const int b = blockIdx.x, tid = threadIdx.x;
    if (b < p.nbGemm) {
        gemm_onto_dev<float>(b, p.x0, p.x1, p.x2, p.go, p.H, p.as_o, p.ad_o);
    } else if (b < p.nbGemm + p.nbF2) {
        fold2_dev((b - p.nbGemm) * 256 + tid, p.W1, p.b1, p.W23b, p.WpT, p.cbuf);
    } else if (b < p.nbGemm + p.nbF2 + p.nbCnt) {
        csr_count_dev((b - p.nbGemm - p.nbF2) * 256 + tid, p.dsc, p.cnt);
    } else {
        mark_dev((b - p.nbGemm - p.nbF2 - p.nbCnt) * 256 + tid, p.lEg, p.rEg,
                 p.EP, p.NP, p.mk, 1, 2);
    }
}

// ---------------------------------------------------------------------------
// L3: scan_tile (1024 elems/block, emits dinv) || mark2
// ---------------------------------------------------------------------------
__device__ void scan_tile_dev(const int* __restrict__ in, int* __restrict__ out,
                              int* __restrict__ bsum, int n, int pn0, int pcnt,
                              float* __restrict__ dinv, int tb, int tid,
                              int* sbuf) {
    const int base = tb * 1024 + tid * 4;
    int v[4];
    int s = 0;
#pragma unroll
    for (int k = 0; k < 4; ++k) {
        const int i = base + k;
        v[k] = (i < n) ? (in[i] + 1) : 0;
        if (i >= pn0 && i < pn0 + pcnt)
            dinv[i - pn0] = rsqrtf(fmaxf((float)v[k], 1e-12f));
        s += v[k];
    }
    sbuf[tid] = s;
    __syncthreads();
    int x = s;
    for (int o = 1; o < 256; o <<= 1) {
        const int t = (tid >= o) ? sbuf[tid - o] : 0;
        __syncthreads();
        x += t;
        sbuf[tid] = x;
        __syncthreads();
    }
    int run = x - s;  // exclusive prefix across threads
#pragma unroll
    for (int k = 0; k < 4; ++k) {
        const int i = base + k;
        if (i < n) out[i] = run;
        run += v[k];
    }
    if (tid == 255) bsum[tb] = x;
}

struct PackScan {
    const int* cnt; int* offs; int* bsum;
    int NV; int pn0; int pcnt; float* dinv;
    const int* lEg; const int* rEg; int EP; int NP; int* mk;
    int nbScan;
};

__global__ __launch_bounds__(256) void k_scan(PackScan p) {
    __shared__ int sbuf[256];
    const int b = blockIdx.x, tid = threadIdx.x;
    if (b < p.nbScan) {
        scan_tile_dev(p.cnt, p.offs, p.bsum, p.NV, p.pn0, p.pcnt, p.dinv, b,
                      tid, sbuf);
    } else {
        mark_dev((b - p.nbScan) * 256 + tid, p.lEg, p.rEg, p.EP, p.NP, p.mk,
                 2, 4);
    }
}

// ---------------------------------------------------------------------------
// L4: fused bsum-prefix + add; also emits offs2 (mutable slot cursors).
// ---------------------------------------------------------------------------
__global__ __launch_bounds__(256) void k_scanfin(int* __restrict__ out,
                                                 int* __restrict__ out2,
                                                 const int* __restrict__ bsum,
                                                 int n, int nbData) {
    __shared__ int sbuf[256];
    const int tb = blockIdx.x, tid = threadIdx.x;
    int pLim = tb < nbData ? tb : nbData;
    int pth = 0;
    for (int j = tid; j < pLim; j += 256) pth += bsum[j];
    sbuf[tid] = pth;
    __syncthreads();
    for (int o = 128; o > 0; o >>= 1) {
        if (tid < o) sbuf[tid] += sbuf[tid + o];
        __syncthreads();
    }
    const int prefix = sbuf[0];
    const int base = tb * 1024 + tid * 4;
#pragma unroll
    for (int k = 0; k < 4; ++k) {
        const int i = base + k;
        if (i < n) {
            const int v = out[i] + prefix;
            out[i] = v;
            out2[i] = v;
        } else if (i == n) {
            out[i] = prefix + ((tb < nbData) ? bsum[tb] : 0);
        }
    }
}

// ---------------------------------------------------------------------------
// Range-parameterized CSR fill. Slot index via returning atomicAdd on offs2
// (pos[] eliminated); patient entries mk-gated BEFORE any offset work.
// ---------------------------------------------------------------------------
struct FillP {
    CsrDesc dsc;
    const int* offs; int* offs2; const int* cnt;
    int* srcl; int4* pedge; const float* dinv;
    const int* lx; const int* rx; const int* mk;
    int NP, pB;
    int eStart, eCount, vStart, vCount;
};

__device__ void fill_dev(const FillP& f, int idx) {
    if (idx < f.eCount) {
        const int i = f.eStart + idx;
        int li = 0;
#pragma unroll
        for (int k = 1; k < 8; ++k) li += (i >= f.dsc.ebase[k]);
        const int j = i - f.dsc.ebase[li];
        const int v = f.dsc.nbase[li] + f.dsc.edst[li][j];
        const int s = f.dsc.esrc[li][j];
        if (li >= 6) {
            const int n2l = v - f.dsc.nbase[6];
            if (f.mk[n2l] == 0) return;   // edge list never read
            const int sg = (li - 6) * f.NP + s;
            const int cidx = atomicAdd(&f.offs2[v], 1);
            int4 rec;
            rec.x = sg;
            rec.y = (li == 7 ? f.rx : f.lx)[s];
            rec.z = __float_as_int(f.dinv[n2l] * f.dinv[sg]);
            rec.w = 0;
            f.pedge[cidx - f.pB] = rec;
        } else {
            const int cidx = atomicAdd(&f.offs2[v], 1);
            f.srcl[cidx] = s;
        }
    } else if (idx < f.eCount + f.vCount) {
        const int v = f.vStart + (idx - f.eCount);
        int li = 0;
#pragma unroll
        for (int k = 1; k < 8; ++k) li += (v >= f.dsc.nbase[k]);
        const int s = v - f.dsc.nbase[li];
        if (li >= 6) {
            const int n2l = v - f.dsc.nbase[6];
            if (f.mk[n2l] == 0) return;
            const int cidx = f.offs[v] + f.cnt[v];   // reserved last slot
            const int sg = (li - 6) * f.NP + s;
            int4 rec;
            rec.x = sg;
            rec.y = (li == 7 ? f.rx : f.lx)[s];
            rec.z = __float_as_int(f.dinv[n2l] * f.dinv[sg]);
            rec.w = 0;
            f.pedge[cidx - f.pB] = rec;
        } else {
            f.srcl[f.offs[v] + f.cnt[v]] = s;
        }
    }
}

__global__ __launch_bounds__(256) void k_fill(FillP f) {
    fill_dev(f, blockIdx.x * 256 + threadIdx.x);
}

// ---------------------------------------------------------------------------
// GAT aggregation: quarter-wave per node, SINGLE PASS (no max subtraction —
// e is bounded ~|12| at these weight scales, exp is safe in fp32 and the
// normalized result is mathematically identical).
// ---------------------------------------------------------------------------
struct GatP {
    int r1, r2;
    int ob0, ob1, ob2;
    const float* b0; const float* b1; const float* b2;
};

__device__ __forceinline__ void acc8(float* acc, float w, const uint4 v) {
    acc[0] += w * bf2f(v.x & 0xffff);
    acc[1] += w * bf2f(v.x >> 16);
    acc[2] += w * bf2f(v.y & 0xffff);
    acc[3] += w * bf2f(v.y >> 16);
    acc[4] += w * bf2f(v.z & 0xffff);
    acc[5] += w * bf2f(v.z >> 16);
    acc[6] += w * bf2f(v.w & 0xffff);
    acc[7] += w * bf2f(v.w >> 16);
}

__device__ void gat_dev(int node, int ql, const ushort* __restrict__ h,
                        const float* __restrict__ as, const float* __restrict__ ad,
                        const int* __restrict__ offs, const int* __restrict__ srcl,
                        const GatP& p, ushort* __restrict__ out, int Mtot) {
    if (node >= Mtot) return;
    const int gid = (node >= p.r1) + (node >= p.r2);
    const int rb = (gid == 0) ? 0 : (gid == 1) ? p.r1 : p.r2;
    const int ob = (gid == 0) ? p.ob0 : (gid == 1) ? p.ob1 : p.ob2;
    const float* bias = (gid == 0) ? p.b0 : (gid == 1) ? p.b1 : p.b2;
    const int local = node - rb;
    const int beg = offs[ob + local], end = offs[ob + local + 1];
    const float adv = ad[node];
    float denom = 0.f;
    float acc[8] = {0.f, 0.f, 0.f, 0.f, 0.f, 0.f, 0.f, 0.f};
    int j = beg;
    for (; j + 2 <= end; j += 2) {
        const int s0 = srcl[j], s1 = srcl[j + 1];
        float e0 = as[rb + s0] + adv; e0 = (e0 > 0.f) ? e0 : 0.2f * e0;
        float e1 = as[rb + s1] + adv; e1 = (e1 > 0.f) ? e1 : 0.2f * e1;
        const float w0 = __expf(e0), w1 = __expf(e1);
        const uint4 v0 = *(const uint4*)(h + (size_t)(rb + s0) * 128 + ql * 8);
        const uint4 v1 = *(const uint4*)(h + (size_t)(rb + s1) * 128 + ql * 8);
        denom += w0 + w1;
        acc8(acc, w0, v0);
        acc8(acc, w1, v1);
    }
    if (j < end) {
        const int s0 = srcl[j];
        float e0 = as[rb + s0] + adv; e0 = (e0 > 0.f) ? e0 : 0.2f * e0;
        const float w0 = __expf(e0);
        const uint4 v0 = *(const uint4*)(h + (size_t)(rb + s0) * 128 + ql * 8);
        denom += w0;
        acc8(acc, w0, v0);
    }
    const float inv = 1.f / denom;
    const float4 bv0 = *(const float4*)(bias + ql * 8);
    const float4 bv1 = *(const float4*)(bias + ql * 8 + 4);
    uint4 o;
    o.x = (uint)f2bf(acc[0] * inv + bv0.x) | ((uint)f2bf(acc[1] * inv + bv0.y) << 16);
    o.y = (uint)f2bf(acc[2] * inv + bv0.z) | ((uint)f2bf(acc[3] * inv + bv0.w) << 16);
    o.z = (uint)f2bf(acc[4] * inv + bv1.x) | ((uint)f2bf(acc[5] * inv + bv1.y) << 16);
    o.w = (uint)f2bf(acc[6] * inv + bv1.z) | ((uint)f2bf(acc[7] * inv + bv1.w) << 16);
    *(uint4*)(out + (size_t)node * 128 + ql * 8) = o;
}

__global__ __launch_bounds__(256) void gat_all(const ushort* __restrict__ h,
                                               const float* __restrict__ as,
                                               const float* __restrict__ ad,
                                               const int* __restrict__ offs,
                                               const int* __restrict__ srcl,
                                               GatP p, ushort* __restrict__ out,
                                               int Mtot) {
    gat_dev(blockIdx.x * 16 + (threadIdx.x >> 4), threadIdx.x & 15, h, as, ad,
            offs, srcl, p, out, Mtot);
}

// L6: gat layer 1 || remaining CSR fill (layer-2 lists + patient)
struct GatFill {
    const ushort* h; const float* as; const float* ad;
    const int* offs; const int* srcl;
    GatP gp; ushort* out; int Mtot; int nbGat;
    FillP f;
};

__global__ __launch_bounds__(256) void k_gat_fill(GatFill g) {
    const int b = blockIdx.x, tid = threadIdx.x;
    if (b < g.nbGat) {
        gat_dev(b * 16 + (tid >> 4), tid & 15, g.h, g.as, g.ad, g.offs, g.srcl,
                g.gp, g.out, g.Mtot);
    } else {
        fill_dev(g.f, (b - g.nbGat) * 256 + tid);
    }
}

// ---------------------------------------------------------------------------
// GCN aggregations: quarter-wave per node, early exit on mk bit.
// ---------------------------------------------------------------------------
__global__ __launch_bounds__(256) void gcn_agg1(const ushort* __restrict__ A3,
                                                const int4* __restrict__ pedge,
                                                const int* __restrict__ offs6,
                                                const float* __restrict__ c1,
                                                ushort* __restrict__ t1,
                                                const int* __restrict__ mk,
                                                int NP2, int pB) {
    const int n2 = blockIdx.x * 16 + (threadIdx.x >> 4);
    const int ql = threadIdx.x & 15;
    if (n2 >= NP2) return;
    if ((mk[n2] & 4) == 0) return;   // t1 row never read
    const int beg = offs6[n2] - pB, end = offs6[n2 + 1] - pB;
    float acc[8] = {0.f, 0.f, 0.f, 0.f, 0.f, 0.f, 0.f, 0.f};
    int j = beg;
    for (; j + 2 <= end; j += 2) {
        const int4 r0 = pedge[j], r1 = pedge[j + 1];
        const float w0 = __int_as_float(r0.z), w1 = __int_as_float(r1.z);
        const uint4 v0 = *(const uint4*)(A3 + (size_t)r0.y * 128 + ql * 8);
        const uint4 v1 = *(const uint4*)(A3 + (size_t)r1.y * 128 + ql * 8);
        acc8(acc, w0, v0);
        acc8(acc, w1, v1);
    }
    if (j < end) {
        const int4 r0 = pedge[j];
        const uint4 v0 = *(const uint4*)(A3 + (size_t)r0.y * 128 + ql * 8);
        acc8(acc, __int_as_float(r0.z), v0);
    }
    const float4 bv0 = *(const float4*)(c1 + ql * 8);
    const float4 bv1 = *(const float4*)(c1 + ql * 8 + 4);
    uint4 o;
    o.x = (uint)f2bf(acc[0] + bv0.x) | ((uint)f2bf(acc[1] + bv0.y) << 16);
    o.y = (uint)f2bf(acc[2] + bv0.z) | ((uint)f2bf(acc[3] + bv0.w) << 16);
    o.z = (uint)f2bf(acc[4] + bv1.x) | ((uint)f2bf(acc[5] + bv1.y) << 16);
    o.w = (uint)f2bf(acc[6] + bv1.z) | ((uint)f2bf(acc[7] + bv1.w) << 16);
    *(uint4*)(t1 + (size_t)n2 * 128 + ql * 8) = o;
}

__device__ __forceinline__ void gcn_q_acc(const ushort* __restrict__ x,
                                          const int4* __restrict__ pedge,
                                          int beg, int end, int ql, float* acc) {
    int j = beg;
    for (; j + 2 <= end; j += 2) {
        const int4 r0 = pedge[j], r1 = pedge[j + 1];
        const float w0 = __int_as_float(r0.z), w1 = __int_as_float(r1.z);
        const uint4 v0 = *(const uint4*)(x + (size_t)r0.x * 128 + ql * 8);
        const uint4 v1 = *(const uint4*)(x + (size_t)r1.x * 128 + ql * 8);
        acc8(acc, w0, v0);
        acc8(acc, w1, v1);
    }
    if (j < end) {
        const int4 r0 = pedge[j];
        const uint4 v0 = *(const uint4*)(x + (size_t)r0.x * 128 + ql * 8);
        acc8(acc, __int_as_float(r0.z), v0);
    }
}

__global__ __launch_bounds__(256) void gcn_agg2(const ushort* __restrict__ t1,
                                                const int4* __restrict__ pedge,
                                                const int* __restrict__ offs6,
                                                const float* __restrict__ c2,
                                                ushort* __restrict__ t2,
                                                const int* __restrict__ mk,
                                                int NP2, int pB) {
    const int n2 = blockIdx.x * 16 + (threadIdx.x >> 4);
    const int ql = threadIdx.x & 15;
    if (n2 >= NP2) return;
    if ((mk[n2] & 2) == 0) return;   // t2 row never read
    const int beg = offs6[n2] - pB, end = offs6[n2 + 1] - pB;
    float acc[8] = {0.f, 0.f, 0.f, 0.f, 0.f, 0.f, 0.f, 0.f};
    gcn_q_acc(t1, pedge, beg, end, ql, acc);
    const float4 bv0 = *(const float4*)(c2 + ql * 8);
    const float4 bv1 = *(const float4*)(c2 + ql * 8 + 4);
    uint4 o;
    o.x = (uint)f2bf(acc[0] + bv0.x) | ((uint)f2bf(acc[1] + bv0.y) << 16);
    o.y = (uint)f2bf(acc[2] + bv0.z) | ((uint)f2bf(acc[3] + bv0.w) << 16);
    o.z = (uint)f2bf(acc[4] + bv1.x) | ((uint)f2bf(acc[5] + bv1.y) << 16);
    o.w = (uint)f2bf(acc[6] + bv1.z) | ((uint)f2bf(acc[7] + bv1.w) << 16);
    *(uint4*)(t2 + (size_t)n2 * 128 + ql * 8) = o;
}

// Fused final layer + cosine: 32 lanes per graph (16 left, 16 right).
__global__ __launch_bounds__(256) void final_cos(const ushort* __restrict__ t2,
                                                 const int4* __restrict__ pedge,
                                                 const int* __restrict__ offs6,
                                                 const int* __restrict__ gfL,
                                                 const int* __restrict__ gfR,
                                                 const float* __restrict__ b3,
                                                 float* __restrict__ out,
                                                 int B, int NP, int pB) {
    const int g = blockIdx.x * 8 + (threadIdx.x >> 5);
    const int l32 = threadIdx.x & 31;
    const int side = l32 >> 4;
    const int ql = l32 & 15;
    if (g >= B) return;
    const int n2 = (side ? NP : 0) + (side ? gfR : gfL)[g];
    const int beg = offs6[n2] - pB, end = offs6[n2 + 1] - pB;
    float acc[8] = {0.f, 0.f, 0.f, 0.f, 0.f, 0.f, 0.f, 0.f};
    gcn_q_acc(t2, pedge, beg, end, ql, acc);
    const float4 bv0 = *(const float4*)(b3 + ql * 8);
    const float4 bv1 = *(const float4*)(b3 + ql * 8 + 4);
    float v[8];
    v[0] = acc[0] + bv0.x; v[1] = acc[1] + bv0.y;
    v[2] = acc[2] + bv0.z; v[3] = acc[3] + bv0.w;
    v[4] = acc[4] + bv1.x; v[5] = acc[5] + bv1.y;
    v[6] = acc[6] + bv1.z; v[7] = acc[7] + bv1.w;
    float num = 0.f, nself = 0.f, nother = 0.f;
#pragma unroll
    for (int j = 0; j < 8; ++j) {
        const float o = __shfl_xor(v[j], 16);
        num += v[j] * o;
        nself += v[j] * v[j];
        nother += o * o;
    }
#pragma unroll
    for (int o1 = 1; o1 < 16; o1 <<= 1) {
        num += __shfl_xor(num, o1);
        nself += __shfl_xor(nself, o1);
        nother += __shfl_xor(nother, o1);
    }
    if (l32 == 0)
        out[g] = num / (fmaxf(sqrtf(nself), 1e-6f) * fmaxf(sqrtf(nother), 1e-6f));
}

// ---------------------------------------------------------------------------
extern "C" void kernel_launch(void* const* d_in, const int* in_sizes, int n_in,
                              void* d_out, int out_size, void* d_ws, size_t ws_size,
                              hipStream_t stream) {
    (void)n_in; (void)ws_size;
    const float* spec = (const float*)d_in[0];
    const float* tabs[3] = {(const float*)d_in[1], (const float*)d_in[2], (const float*)d_in[3]};
    const float* ontW[3] = {(const float*)d_in[4], (const float*)d_in[8], (const float*)d_in[12]};
    const float* ontAs[3] = {(const float*)d_in[5], (const float*)d_in[9], (const float*)d_in[13]};
    const float* ontAd[3] = {(const float*)d_in[6], (const float*)d_in[10], (const float*)d_in[14]};
    const float* ontB[3] = {(const float*)d_in[7], (const float*)d_in[11], (const float*)d_in[15]};
    const float* gcnW[3] = {(const float*)d_in[16], (const float*)d_in[18], (const float*)d_in[20]};
    const float* gcnB[3] = {(const float*)d_in[17], (const float*)d_in[19], (const float*)d_in[21]};
    const int* e1s[3] = {(const int*)d_in[22], (const int*)d_in[24], (const int*)d_in[26]};
    const int* e2s[3] = {(const int*)d_in[23], (const int*)d_in[25], (const int*)d_in[27]};
    const int* maps[3] = {(const int*)d_in[28], (const int*)d_in[29], (const int*)d_in[30]};
    const int* left_x = (const int*)d_in[31];
    const int* right_x = (const int*)d_in[32];
    const int* left_eg = (const int*)d_in[33];
    const int* right_eg = (const int*)d_in[34];
    const int* left_batch = (const int*)d_in[35];
    const int* right_batch = (const int*)d_in[36];

    int Ms[3] = {in_sizes[1] / HID, in_sizes[2] / HID, in_sizes[3] / HID};
    int E1s[3] = {in_sizes[22] / 2, in_sizes[24] / 2, in_sizes[26] / 2};
    int E2s[3] = {in_sizes[23] / 2, in_sizes[25] / 2, in_sizes[27] / 2};
    int Ls[3] = {in_sizes[28], in_sizes[29], in_sizes[30]};
    const int NP = in_sizes[31];
    const int EP = in_sizes[33] / 2;
    const int B = out_size;
    const long ALL = 1 + (long)Ls[0] + Ls[1] + Ls[2];
    const int Mtot = Ms[0] + Ms[1] + Ms[2];
    const int r1 = Ms[0], r2 = Ms[0] + Ms[1];

    // ---- batched CSR descriptor (layer-1 lists first) ----
    CsrDesc dsc;
    int eCnt[8], nCnt[8];
    for (int i = 0; i < 3; ++i) {
        dsc.esrc[i] = e1s[i];     dsc.edst[i] = e1s[i] + E1s[i];
        eCnt[i] = E1s[i];         nCnt[i] = Ms[i];
        dsc.esrc[3 + i] = e2s[i]; dsc.edst[3 + i] = e2s[i] + E2s[i];
        eCnt[3 + i] = E2s[i];     nCnt[3 + i] = Ms[i];
    }
    dsc.esrc[6] = left_eg;  dsc.edst[6] = left_eg + EP;  eCnt[6] = EP; nCnt[6] = NP;
    dsc.esrc[7] = right_eg; dsc.edst[7] = right_eg + EP; eCnt[7] = EP; nCnt[7] = NP;
    dsc.ebase[0] = 0;
    int nb_acc = 0;
    for (int i = 0; i < 8; ++i) {
        dsc.ebase[i + 1] = dsc.ebase[i] + eCnt[i];
        dsc.nbase[i] = nb_acc;
        nb_acc += nCnt[i];
    }
    const int NV = nb_acc;
    dsc.nbase[8] = NV;
    dsc.totE = dsc.ebase[8];
    const int totEntries = dsc.totE + NV;
    const int pB = dsc.ebase[6] + dsc.nbase[6];
    const int pEntries = totEntries - pB;

    // ---- workspace layout ----
    char* ws = (char*)d_ws;
    size_t off = 0;
    auto alloc = [&](size_t bytes) -> void* {
        off = (off + 255) & ~(size_t)255;
        void* p = ws + off;
        off += bytes;
        return p;
    };
    ushort* wt4 = (ushort*)alloc((size_t)4 * 16384 * 2);   // 3 ont Wt + WpT
    float* W23b = (float*)alloc((size_t)129 * 128 * 4);
    float* cbuf = (float*)alloc((size_t)256 * 4);          // c1 | c2
    ushort* A3 = (ushort*)alloc((size_t)ALL * HID * 2);
    int* cnt = (int*)alloc((size_t)NV * 4);
    int* offs = (int*)alloc((size_t)(NV + 1) * 4);
    int* offs2 = (int*)alloc((size_t)NV * 4);
    int* srcl = (int*)alloc((size_t)pB * 4);
    int4* pedge = (int4*)alloc((size_t)pEntries * 16);
    int* bsum = (int*)alloc(1025 * 4);
    float* dinv = (float*)alloc((size_t)2 * NP * 4);
    float* as = (float*)alloc((size_t)Mtot * 4);
    float* ad = (float*)alloc((size_t)Mtot * 4);
    int* gfL = (int*)alloc((size_t)(B + 1) * 4);
    int* gfR = (int*)alloc((size_t)(B + 1) * 4);
    int* mk = (int*)alloc((size_t)2 * NP * 4);
    ushort* t1 = (ushort*)alloc((size_t)2 * NP * HID * 2);
    ushort* big = (ushort*)alloc((size_t)2 * NP * HID * 2);
    ushort* hbuf = big;                              // [Mtot x 128] bf16
    ushort* obuf = big + (size_t)Mtot * HID;         // [Mtot x 128] bf16
    ushort* t2 = big;                                // [2NP x 128] bf16 (later)

    const ushort* wtOnt[3] = {wt4, wt4 + 16384, wt4 + 2 * 16384};
    ushort* WpT = wt4 + 3 * 16384;
    const float* c1 = cbuf;
    const float* c2 = cbuf + 128;

    // ---- L1: prep (fold1 || wtrans x3 || init cnt/mk/gf) ----
    PackPrep pp;
    pp.W2 = gcnW[1]; pp.b2 = gcnB[1]; pp.W3 = gcnW[2]; pp.W23b = W23b;
    pp.wsrc[0] = ontW[0]; pp.wsrc[1] = ontW[1]; pp.wsrc[2] = ontW[2];
    pp.wt_out = wt4;
    pp.cnt = cnt; pp.NV = NV;
    pp.bL = left_batch; pp.bR = right_batch; pp.NP = NP;
    pp.gfL = gfL; pp.gfR = gfR; pp.mk = mk;
    pp.nbF1 = cdiv_i(129 * 128, 256);
    pp.nbWT = cdiv_i(3 * 16384, 256);
    pp.nbInit = cdiv_i(imax_i(NV, 2 * NP), 256);
    k_prep<<<pp.nbF1 + pp.nbWT + pp.nbInit, 256, 0, stream>>>(pp);

    // ---- ontology GEMM descriptor ----
    GOnto go;
    go.Wt0 = wtOnt[0]; go.Wt1 = wtOnt[1]; go.Wt2 = wtOnt[2];
    go.s0 = ontAs[0]; go.s1 = ontAs[1]; go.s2 = ontAs[2];
    go.d0 = ontAd[0]; go.d1 = ontAd[1]; go.d2 = ontAd[2];
    go.bs1 = cdiv_i(Ms[0], 128);
    go.bs2 = go.bs1 + cdiv_i(Ms[1], 128);
    const int totBlk = go.bs2 + cdiv_i(Ms[2], 128);
    go.r1 = r1; go.r2 = r2; go.r3 = Mtot;

    // ---- L2: big pack (zero LDS): gemm L1 || fold2 || count || mark1 ----
    PackBig pg;
    pg.x0 = tabs[0]; pg.x1 = tabs[1]; pg.x2 = tabs[2];
    pg.go = go; pg.H = hbuf; pg.as_o = as; pg.ad_o = ad;
    pg.W1 = gcnW[0]; pg.b1 = gcnB[0]; pg.W23b = W23b;
    pg.WpT = WpT; pg.cbuf = cbuf;
    pg.dsc = dsc; pg.cnt = cnt;
    pg.lEg = left_eg; pg.rEg = right_eg; pg.EP = EP; pg.NP = NP; pg.mk = mk;
    pg.nbGemm = totBlk;
    pg.nbF2 = cdiv_i(130 * 128, 256);
    pg.nbCnt = cdiv_i(dsc.totE, 256);
    const int nbMark = cdiv_i(2 * EP + 2 * NP, 256);
    k_big1<<<pg.nbGemm + pg.nbF2 + pg.nbCnt + nbMark, 256, 0, stream>>>(pg);

    // ---- L3: scan(+dinv) || mark2 ----
    PackScan psn;
    psn.cnt = cnt; psn.offs = offs; psn.bsum = bsum;
    psn.NV = NV; psn.pn0 = dsc.nbase[6]; psn.pcnt = 2 * NP; psn.dinv = dinv;
    psn.lEg = left_eg; psn.rEg = right_eg; psn.EP = EP; psn.NP = NP; psn.mk = mk;
    psn.nbScan = cdiv_i(NV, 1024);
    k_scan<<<psn.nbScan + nbMark, 256, 0, stream>>>(psn);

    // ---- L4: scan finalize (writes offs + offs2 slot cursors) ----
    k_scanfin<<<cdiv_i(NV + 1, 1024), 256, 0, stream>>>(offs, offs2, bsum, NV,
                                                        psn.nbScan);

    // ---- shared fill params ----
    FillP fb;
    fb.dsc = dsc; fb.offs = offs; fb.offs2 = offs2; fb.cnt = cnt;
    fb.srcl = srcl; fb.pedge = pedge; fb.dinv = dinv;
    fb.lx = left_x; fb.rx = right_x; fb.mk = mk;
    fb.NP = NP; fb.pB = pB;

    // ---- L5: layer-1 ontology CSR fill (critical path to gat1) ----
    FillP fo = fb;
    fo.eStart = 0;             fo.eCount = dsc.ebase[3];
    fo.vStart = 0;             fo.vCount = dsc.nbase[3];
    k_fill<<<cdiv_i(fo.eCount + fo.vCount, 256), 256, 0, stream>>>(fo);

    // ---- L6: gat layer 1 || layer-2 + patient CSR fill ----
    GatFill gf;
    gf.h = hbuf; gf.as = as; gf.ad = ad; gf.offs = offs; gf.srcl = srcl;
    gf.gp = GatP{r1, r2, dsc.nbase[0], dsc.nbase[1], dsc.nbase[2],
                 ontB[0], ontB[1], ontB[2]};
    gf.out = obuf; gf.Mtot = Mtot;
    gf.nbGat = cdiv_i(Mtot, 16);
    gf.f = fb;
    gf.f.eStart = dsc.ebase[3]; gf.f.eCount = dsc.totE - dsc.ebase[3];
    gf.f.vStart = dsc.nbase[3]; gf.f.vCount = NV - dsc.nbase[3];
    k_gat_fill<<<gf.nbGat + cdiv_i(gf.f.eCount + gf.f.vCount, 256), 256, 0,
                 stream>>>(gf);

    // ---- L7, L8: ontology GEMM layer 2, GAT layer 2 ----
    gemm_onto_l2<<<totBlk, 256, 0, stream>>>(obuf, obuf + (size_t)r1 * HID,
                                             obuf + (size_t)r2 * HID, go, hbuf,
                                             as, ad);
    const GatP gp1{r1, r2, dsc.nbase[3], dsc.nbase[4], dsc.nbase[5],
                   ontB[0], ontB[1], ontB[2]};
    gat_all<<<cdiv_i(Mtot, 16), 256, 0, stream>>>(hbuf, as, ad, offs, srcl, gp1,
                                                  obuf, Mtot);

    // ---- L9: patient GEMM with fused emb gather ----
    EmbSrc es;
    es.spec = spec; es.oE = obuf;
    es.m0 = maps[0]; es.m1 = maps[1]; es.m2 = maps[2];
    es.lb2 = 1 + Ls[0]; es.lb3 = 1 + Ls[0] + Ls[1];
    es.r1 = r1; es.r2 = r2;
    gemm_pat<<<cdiv_i(ALL, 256), 256, 0, stream>>>(es, WpT, A3, (int)ALL);

    // ---- L10..L12: sparsified aggregations + fused final ----
    const int* offs6 = offs + dsc.nbase[6];
    gcn_agg1<<<cdiv_i(2 * NP, 16), 256, 0, stream>>>(A3, pedge, offs6, c1, t1,
                                                     mk, 2 * NP, pB);
    gcn_agg2<<<cdiv_i(2 * NP, 16), 256, 0, stream>>>(t1, pedge, offs6, c2, t2,
                                                     mk, 2 * NP, pB);
    final_cos<<<cdiv_i(B, 8), 256, 0, stream>>>(t2, pedge, offs6, gfL, gfR,
                                                gcnB[2], (float*)d_out, B, NP, pB);
}